// Round 2
// baseline (432.174 us; speedup 1.0000x reference)
//
#include <hip/hip_runtime.h>
#include <math.h>

// ---- problem constants -------------------------------------------------
constexpr int B_    = 4;
constexpr int S_    = 2048;
constexpr int F_    = 512;     // IN_FEATURES
constexpr int H_    = 8;       // NUM_HEADS
constexpr int D_    = 32;      // HEAD_DIM
constexpr int HID_  = 256;     // H_*D_
constexpr int NA_   = 16;      // NUM_ACTIONS
constexpr int ROWS_ = B_ * S_; // 8192
constexpr int CHUNK_= 64;      // steps per scan chunk
constexpr int NC_   = S_ / CHUNK_;  // 32 chunks
constexpr int T_    = 16;      // timesteps staged per LDS tile
constexpr int NT_   = CHUNK_ / T_;  // 4 tiles per chunk
constexpr int BH_   = B_ * H_;      // 32

__device__ __forceinline__ float sigmoidf_(float x) { return 1.0f / (1.0f + expf(-x)); }

// ---- K1a: fused q/k/v projection GEMM  (8192x512 @ 512x256, x3 via z) --
// 128x128 tile, BK=16, 256 threads, 8x8 micro-tile. fp32 (no fp32 MFMA on CDNA4).
__global__ __launch_bounds__(256) void gemm_x_kernel(
    const float* __restrict__ x,
    const float* __restrict__ Wq, const float* __restrict__ Wk, const float* __restrict__ Wv,
    float* __restrict__ qo, float* __restrict__ ko, float* __restrict__ vo)
{
    __shared__ float As[16][128];   // transposed: As[kk][row]
    __shared__ float Bs[16][128];
    const float* W; float* C;
    if (blockIdx.z == 0)      { W = Wq; C = qo; }
    else if (blockIdx.z == 1) { W = Wk; C = ko; }
    else                      { W = Wv; C = vo; }
    const int t   = threadIdx.x;
    const int tc  = t & 15;          // 16 col-threads
    const int tr  = t >> 4;          // 16 row-threads
    const int row0 = blockIdx.x * 128;
    const int col0 = blockIdx.y * 128;

    float acc[8][8];
    #pragma unroll
    for (int i = 0; i < 8; i++)
        #pragma unroll
        for (int j = 0; j < 8; j++) acc[i][j] = 0.0f;

    for (int k0 = 0; k0 < F_; k0 += 16) {
        #pragma unroll
        for (int i = 0; i < 2; i++) {
            int slot = t + i * 256;                // 512 float4 slots
            int r  = slot >> 2, kq = slot & 3;     // A: 128 rows x 4 quads
            float4 a4 = *(const float4*)(x + (size_t)(row0 + r) * F_ + k0 + kq * 4);
            As[kq*4+0][r] = a4.x; As[kq*4+1][r] = a4.y;
            As[kq*4+2][r] = a4.z; As[kq*4+3][r] = a4.w;
            int kk = slot >> 5, cq = slot & 31;    // B: 16 k x 32 quads
            *(float4*)&Bs[kk][cq*4] =
                *(const float4*)(W + (size_t)(k0 + kk) * HID_ + col0 + cq * 4);
        }
        __syncthreads();
        #pragma unroll
        for (int kk = 0; kk < 16; kk++) {
            float a[8], b[8];
            *(float4*)&a[0] = *(float4*)&As[kk][tr*8];
            *(float4*)&a[4] = *(float4*)&As[kk][tr*8+4];
            *(float4*)&b[0] = *(float4*)&Bs[kk][tc*8];
            *(float4*)&b[4] = *(float4*)&Bs[kk][tc*8+4];
            #pragma unroll
            for (int i = 0; i < 8; i++)
                #pragma unroll
                for (int j = 0; j < 8; j++) acc[i][j] += a[i] * b[j];
        }
        __syncthreads();
    }
    #pragma unroll
    for (int i = 0; i < 8; i++) {
        #pragma unroll
        for (int jq = 0; jq < 2; jq++) {
            float4 r4 = make_float4(acc[i][jq*4+0], acc[i][jq*4+1],
                                    acc[i][jq*4+2], acc[i][jq*4+3]);
            *(float4*)(C + (size_t)(row0 + tr*8 + i) * HID_ + col0 + tc*8 + jq*4) = r4;
        }
    }
}

// ---- K1b: beta/alpha projection (8192x512 @ 512x8, x2) + sigmoid -------
__global__ __launch_bounds__(256) void gemm_ba_kernel(
    const float* __restrict__ x, const float* __restrict__ Wb, const float* __restrict__ Wa,
    float* __restrict__ betab, float* __restrict__ alphab)
{
    __shared__ float xs[16][F_];     // 32 KB
    const int t = threadIdx.x;
    const int row0 = blockIdx.x * 16;
    #pragma unroll
    for (int i = 0; i < 8; i++) {
        int slot = t + i * 256;              // 2048 float4 slots
        int r = slot >> 7, kq = slot & 127;
        *(float4*)&xs[r][kq*4] = *(const float4*)(x + (size_t)(row0 + r) * F_ + kq * 4);
    }
    __syncthreads();
    const int j = t & 15, mloc = t >> 4;
    const float* W = (j < 8) ? Wb : Wa;
    const int jc = j & 7;
    float acc = 0.0f;
    #pragma unroll 4
    for (int kk = 0; kk < F_; kk++) acc += xs[mloc][kk] * W[kk * 8 + jc];
    float r = sigmoidf_(acc);
    if (j < 8) betab[(row0 + mloc) * 8 + jc] = r;
    else       alphab[(row0 + mloc) * 8 + jc] = r;
}

// ---- K1c: action projections (K=16) ku/vu/gamma ------------------------
__global__ __launch_bounds__(256) void gemm_act_kernel(
    const float* __restrict__ act, const float* __restrict__ Wku,
    const float* __restrict__ Wvu, const float* __restrict__ Wg,
    float* __restrict__ ku, float* __restrict__ vu, float* __restrict__ bg)
{
    int o = blockIdx.x * 256 + threadIdx.x;
    const int total = ROWS_ * 520;           // 256 + 256 + 8
    if (o >= total) return;
    int row = o / 520;
    int col = o - row * 520;
    const float* a = act + (size_t)row * NA_;
    float acc = 0.0f;
    if (col < 256) {
        #pragma unroll
        for (int kk = 0; kk < NA_; kk++) acc += a[kk] * Wku[kk * HID_ + col];
        ku[(size_t)row * HID_ + col] = acc;
    } else if (col < 512) {
        int c = col - 256;
        #pragma unroll
        for (int kk = 0; kk < NA_; kk++) acc += a[kk] * Wvu[kk * HID_ + c];
        vu[(size_t)row * HID_ + c] = acc;
    } else {
        int c = col - 512;
        #pragma unroll
        for (int kk = 0; kk < NA_; kk++) acc += a[kk] * Wg[kk * H_ + c];
        bg[(size_t)row * H_ + c] = sigmoidf_(acc);
    }
}

// ---- K2: silu + l2norm (per 32-elem head group) for q, k, ku, in place -
__global__ __launch_bounds__(256) void silu_norm_kernel(
    float* __restrict__ q, float* __restrict__ k, float* __restrict__ ku)
{
    const int t = threadIdx.x;
    const int d = t & 31;
    const size_t g = (size_t)blockIdx.x * 8 + (t >> 5);   // head-group id
    const size_t idx = g * 32 + d;
    float* bufs[3] = { q, k, ku };
    #pragma unroll
    for (int a = 0; a < 3; a++) {
        float x = bufs[a][idx];
        float v = x * (1.0f / (1.0f + expf(-x)));
        float ss = v * v;
        ss += __shfl_xor(ss, 1);  ss += __shfl_xor(ss, 2);  ss += __shfl_xor(ss, 4);
        ss += __shfl_xor(ss, 8);  ss += __shfl_xor(ss, 16);
        bufs[a][idx] = v * rsqrtf(ss + 1e-6f);
    }
}

// ---- K3a: per-chunk (cumA, cumB) via rank-1 recurrences ----------------
// 64 threads = 1 wave; thread t: row i=t>>1, col half j0=(t&1)*16.
// T_=16 timesteps staged per LDS tile; next tile prefetched into registers.
__global__ __launch_bounds__(64) void scan_pass1(
    const float* __restrict__ kbuf, const float* __restrict__ vbuf,
    const float* __restrict__ kubuf, const float* __restrict__ vubuf,
    const float* __restrict__ betab, const float* __restrict__ alphab,
    const float* __restrict__ gammab, const float* __restrict__ mask,
    float* __restrict__ cumA, float* __restrict__ cumB)
{
    const int bh = blockIdx.x;     // 0..31
    const int c  = blockIdx.y;     // 0..NC_-1
    const int b  = bh >> 3, h = bh & 7;
    const int t  = threadIdx.x;
    const int i  = t >> 1;
    const int j0 = (t & 1) * 16;
    __shared__ float lk [T_][32];
    __shared__ float lv [T_][32];
    __shared__ float lku[T_][32];
    __shared__ float lvu[T_][32];
    __shared__ float lsc[T_][4];   // 0:beta 1:alpha*(1-mask) 2:gamma

    float M[16], Cc[16];
    #pragma unroll
    for (int jj = 0; jj < 16; jj++) { M[jj] = (i == j0 + jj) ? 1.0f : 0.0f; Cc[jj] = 0.0f; }

    auto stage = [&](int tile, float4* pk, float4* pv, float4* pku, float4* pvu,
                     float& sb, float& sa, float& sg) {
        const int row_base = b * S_ + c * CHUNK_ + tile * T_;
        #pragma unroll
        for (int u = 0; u < 2; u++) {
            int slot = t + u * 64;           // 128 float4 slots: 16 rows x 8 quads
            int r = slot >> 3, q = slot & 7;
            const size_t gb = (size_t)(row_base + r) * HID_ + h * D_ + q * 4;
            pk[u]  = *(const float4*)(kbuf  + gb);
            pv[u]  = *(const float4*)(vbuf  + gb);
            pku[u] = *(const float4*)(kubuf + gb);
            pvu[u] = *(const float4*)(vubuf + gb);
        }
        const int r = t & 15;
        const int rowi = row_base + r;
        if (t < 16)       sb = betab [(size_t)rowi * H_ + h];
        else if (t < 32)  sa = alphab[(size_t)rowi * H_ + h] * (1.0f - mask[rowi]);
        else if (t < 48)  sg = gammab[(size_t)rowi * H_ + h];
    };
    auto commit = [&](float4* pk, float4* pv, float4* pku, float4* pvu,
                      float sb, float sa, float sg) {
        #pragma unroll
        for (int u = 0; u < 2; u++) {
            int slot = t + u * 64;
            int r = slot >> 3, q = slot & 7;
            *(float4*)&lk [r][q*4] = pk[u];
            *(float4*)&lv [r][q*4] = pv[u];
            *(float4*)&lku[r][q*4] = pku[u];
            *(float4*)&lvu[r][q*4] = pvu[u];
        }
        const int r = t & 15;
        if (t < 16)       lsc[r][0] = sb;
        else if (t < 32)  lsc[r][1] = sa;
        else if (t < 48)  lsc[r][2] = sg;
    };

    float4 pk[2], pv[2], pku[2], pvu[2]; float sb = 0, sa = 0, sg = 0;
    stage(0, pk, pv, pku, pvu, sb, sa, sg);

    for (int tile = 0; tile < NT_; ++tile) {
        commit(pk, pv, pku, pvu, sb, sa, sg);
        __syncthreads();
        float4 nk[2], nv[2], nku[2], nvu[2]; float nb = 0, na = 0, ng = 0;
        if (tile + 1 < NT_) stage(tile + 1, nk, nv, nku, nvu, nb, na, ng);

        #pragma unroll
        for (int sl = 0; sl < T_; sl++) {
            const float vi  = lv [sl][i];
            const float vui = lvu[sl][i];
            const float bet = lsc[sl][0];
            const float a   = lsc[sl][1];
            const float bgm = lsc[sl][2];
            float kj[16], kuj[16];
            #pragma unroll
            for (int jj = 0; jj < 16; jj++) { kj[jj] = lk[sl][j0 + jj]; kuj[jj] = lku[sl][j0 + jj]; }
            float pd = 0.0f;
            #pragma unroll
            for (int jj = 0; jj < 16; jj++) pd += kuj[jj] * kj[jj];
            const float duk = pd + __shfl_xor(pd, 1);
            float mk = 0.0f, ck = 0.0f;
            #pragma unroll
            for (int jj = 0; jj < 16; jj++) { mk += M[jj] * kj[jj]; ck += Cc[jj] * kj[jj]; }
            mk += __shfl_xor(mk, 1);
            ck += __shfl_xor(ck, 1);
            const float abk_m   = a * bet * mk;
            const float ck_coef = bet * vi - a * bet * ck;
            const float wu      = bgm * vui;
            const float bduk    = bet * duk;
            #pragma unroll
            for (int jj = 0; jj < 16; jj++) {
                const float kv = kj[jj];
                const float w  = kuj[jj] - bduk * kv;         // (ku^T @ delta)[j]
                M[jj]  = a * M[jj]  - abk_m   * kv;           // M @ decay
                Cc[jj] = a * Cc[jj] + ck_coef * kv + wu * w;  // C @ decay + update
            }
        }
        __syncthreads();
        #pragma unroll
        for (int u = 0; u < 2; u++) { pk[u] = nk[u]; pv[u] = nv[u]; pku[u] = nku[u]; pvu[u] = nvu[u]; }
        sb = nb; sa = na; sg = ng;
    }
    const size_t ofs = ((size_t)(bh * NC_ + c)) * 1024 + (size_t)i * 32 + j0;
    #pragma unroll
    for (int u = 0; u < 4; u++) {
        *(float4*)(cumA + ofs + u*4) = make_float4(M[u*4],  M[u*4+1],  M[u*4+2],  M[u*4+3]);
        *(float4*)(cumB + ofs + u*4) = make_float4(Cc[u*4], Cc[u*4+1], Cc[u*4+2], Cc[u*4+3]);
    }
}

// ---- K3b: sequential chunk composition; emits Sstart per chunk + carry --
// 1024 threads: one per state element (i = t>>5, j = t&31). Next chunk's
// cumA/cumB prefetched into registers to overlap the 32-MAC compute.
__global__ __launch_bounds__(1024) void scan_pass2(
    const float* __restrict__ carry, const float* __restrict__ cumA,
    const float* __restrict__ cumB, float* __restrict__ Sstart,
    float* __restrict__ carry_out)
{
    const int bh = blockIdx.x;
    const int t  = threadIdx.x;
    const int i  = t >> 5;
    const int j  = t & 31;
    __shared__ float Ssh[32][33];
    __shared__ float Ash[32][33];
    const size_t idx = (size_t)i * 32 + j;
    float Sv = carry[(size_t)bh * 1024 + idx];

    float Anext = cumA[((size_t)(bh * NC_)) * 1024 + idx];
    float Bnext = cumB[((size_t)(bh * NC_)) * 1024 + idx];
    for (int c = 0; c < NC_; c++) {
        const size_t ofs = ((size_t)(bh * NC_ + c)) * 1024;
        Sstart[ofs + idx] = Sv;
        Ssh[i][j] = Sv;
        Ash[i][j] = Anext;
        const float Bcur = Bnext;
        __syncthreads();
        if (c + 1 < NC_) {                 // issue next chunk's loads early
            const size_t ofs2 = ofs + 1024;
            Anext = cumA[ofs2 + idx];
            Bnext = cumB[ofs2 + idx];
        }
        float acc = Bcur;
        #pragma unroll 8
        for (int m = 0; m < 32; m++) acc += Ssh[i][m] * Ash[m][j];
        __syncthreads();
        Sv = acc;
    }
    carry_out[(size_t)bh * 1024 + idx] = Sv;
}

// ---- K3c: replay each chunk from Sstart, emit out = S_new . q ----------
__global__ __launch_bounds__(64) void scan_pass3(
    const float* __restrict__ qbuf, const float* __restrict__ kbuf,
    const float* __restrict__ vbuf, const float* __restrict__ kubuf,
    const float* __restrict__ vubuf, const float* __restrict__ betab,
    const float* __restrict__ alphab, const float* __restrict__ gammab,
    const float* __restrict__ mask, const float* __restrict__ Sstart,
    float* __restrict__ outpre)
{
    const int bh = blockIdx.x, c = blockIdx.y;
    const int b  = bh >> 3, h = bh & 7;
    const int t  = threadIdx.x;
    const int i  = t >> 1;
    const int j0 = (t & 1) * 16;
    __shared__ float lk [T_][32];
    __shared__ float lq [T_][32];
    __shared__ float lv [T_][32];
    __shared__ float lku[T_][32];
    __shared__ float lvu[T_][32];
    __shared__ float lsc[T_][4];

    float Sv[16];
    const size_t sofs = ((size_t)(bh * NC_ + c)) * 1024 + (size_t)i * 32 + j0;
    #pragma unroll
    for (int u = 0; u < 4; u++) {
        float4 s4 = *(const float4*)(Sstart + sofs + u*4);
        Sv[u*4] = s4.x; Sv[u*4+1] = s4.y; Sv[u*4+2] = s4.z; Sv[u*4+3] = s4.w;
    }

    auto stage = [&](int tile, float4* pk, float4* pq, float4* pv, float4* pku, float4* pvu,
                     float& sb, float& sa, float& sg) {
        const int row_base = b * S_ + c * CHUNK_ + tile * T_;
        #pragma unroll
        for (int u = 0; u < 2; u++) {
            int slot = t + u * 64;
            int r = slot >> 3, q = slot & 7;
            const size_t gb = (size_t)(row_base + r) * HID_ + h * D_ + q * 4;
            pk[u]  = *(const float4*)(kbuf  + gb);
            pq[u]  = *(const float4*)(qbuf  + gb);
            pv[u]  = *(const float4*)(vbuf  + gb);
            pku[u] = *(const float4*)(kubuf + gb);
            pvu[u] = *(const float4*)(vubuf + gb);
        }
        const int r = t & 15;
        const int rowi = row_base + r;
        if (t < 16)       sb = betab [(size_t)rowi * H_ + h];
        else if (t < 32)  sa = alphab[(size_t)rowi * H_ + h] * (1.0f - mask[rowi]);
        else if (t < 48)  sg = gammab[(size_t)rowi * H_ + h];
    };
    auto commit = [&](float4* pk, float4* pq, float4* pv, float4* pku, float4* pvu,
                      float sb, float sa, float sg) {
        #pragma unroll
        for (int u = 0; u < 2; u++) {
            int slot = t + u * 64;
            int r = slot >> 3, q = slot & 7;
            *(float4*)&lk [r][q*4] = pk[u];
            *(float4*)&lq [r][q*4] = pq[u];
            *(float4*)&lv [r][q*4] = pv[u];
            *(float4*)&lku[r][q*4] = pku[u];
            *(float4*)&lvu[r][q*4] = pvu[u];
        }
        const int r = t & 15;
        if (t < 16)       lsc[r][0] = sb;
        else if (t < 32)  lsc[r][1] = sa;
        else if (t < 48)  lsc[r][2] = sg;
    };

    float4 pk[2], pq[2], pv[2], pku[2], pvu[2]; float sb = 0, sa = 0, sg = 0;
    stage(0, pk, pq, pv, pku, pvu, sb, sa, sg);

    for (int tile = 0; tile < NT_; ++tile) {
        commit(pk, pq, pv, pku, pvu, sb, sa, sg);
        __syncthreads();
        float4 nk[2], nq[2], nv[2], nku[2], nvu[2]; float nb = 0, na = 0, ng = 0;
        if (tile + 1 < NT_) stage(tile + 1, nk, nq, nv, nku, nvu, nb, na, ng);

        const int row_base = b * S_ + c * CHUNK_ + tile * T_;
        #pragma unroll
        for (int sl = 0; sl < T_; sl++) {
            const float vi  = lv [sl][i];
            const float vui = lvu[sl][i];
            const float bet = lsc[sl][0];
            const float a   = lsc[sl][1];
            const float bgm = lsc[sl][2];
            float kj[16], kuj[16], qj[16];
            #pragma unroll
            for (int jj = 0; jj < 16; jj++) {
                kj[jj] = lk[sl][j0 + jj]; kuj[jj] = lku[sl][j0 + jj]; qj[jj] = lq[sl][j0 + jj];
            }
            float pd = 0.0f;
            #pragma unroll
            for (int jj = 0; jj < 16; jj++) pd += kuj[jj] * kj[jj];
            const float duk = pd + __shfl_xor(pd, 1);
            float sk = 0.0f;
            #pragma unroll
            for (int jj = 0; jj < 16; jj++) sk += Sv[jj] * kj[jj];
            sk += __shfl_xor(sk, 1);
            const float coef_k = bet * vi - a * bet * sk;
            const float wu     = bgm * vui;
            const float bduk   = bet * duk;
            float op = 0.0f;
            #pragma unroll
            for (int jj = 0; jj < 16; jj++) {
                const float kv = kj[jj];
                const float w  = kuj[jj] - bduk * kv;
                Sv[jj] = a * Sv[jj] + coef_k * kv + wu * w;
                op += Sv[jj] * qj[jj];
            }
            op += __shfl_xor(op, 1);
            if ((t & 1) == 0)
                outpre[(size_t)(row_base + sl) * HID_ + h * D_ + i] = op;
        }
        __syncthreads();
        #pragma unroll
        for (int u = 0; u < 2; u++) {
            pk[u] = nk[u]; pq[u] = nq[u]; pv[u] = nv[u]; pku[u] = nku[u]; pvu[u] = nvu[u];
        }
        sb = nb; sa = na; sg = ng;
    }
}

// ---- K4: RMS norm + scale + out GEMM (8192x256 @ 256x512) + bias -------
__global__ __launch_bounds__(256) void out_kernel(
    const float* __restrict__ outpre, const float* __restrict__ rms_scale,
    const float* __restrict__ Wout, const float* __restrict__ bout,
    float* __restrict__ y)
{
    __shared__ float xs[32][HID_];   // 32 KB
    __shared__ float rinv[32];
    const int t = threadIdx.x;
    const int row0 = blockIdx.x * 32;
    const int col0 = blockIdx.y * 128;
    #pragma unroll
    for (int i = 0; i < 8; i++) {
        int slot = t + i * 256;              // 2048 float4 slots
        int r = slot >> 6, kq = slot & 63;
        *(float4*)&xs[r][kq*4] = *(const float4*)(outpre + (size_t)(row0 + r) * HID_ + kq * 4);
    }
    __syncthreads();
    {
        const int r = t >> 3, s0 = (t & 7) * 32;
        float ss = 0.0f;
        #pragma unroll
        for (int u = 0; u < 32; u++) { float v = xs[r][s0 + u]; ss += v * v; }
        ss += __shfl_xor(ss, 1); ss += __shfl_xor(ss, 2); ss += __shfl_xor(ss, 4);
        if ((t & 7) == 0) rinv[r] = rsqrtf(ss * (1.0f / HID_) + 1e-6f);
    }
    __syncthreads();
    {
        const int r = t >> 3, s0 = (t & 7) * 32;
        const float ri = rinv[r];
        #pragma unroll
        for (int u = 0; u < 32; u++) xs[r][s0 + u] *= ri * rms_scale[s0 + u];
    }
    __syncthreads();
    const int tc = t & 31, tr = t >> 5;      // 32 col-threads x 8 row-threads
    float acc[4][4];
    #pragma unroll
    for (int u = 0; u < 4; u++)
        #pragma unroll
        for (int v = 0; v < 4; v++) acc[u][v] = 0.0f;
    for (int kk = 0; kk < HID_; kk++) {
        float a[4];
        #pragma unroll
        for (int u = 0; u < 4; u++) a[u] = xs[tr*4 + u][kk];
        const float4 bv = *(const float4*)(Wout + (size_t)kk * F_ + col0 + tc * 4);
        const float bb[4] = { bv.x, bv.y, bv.z, bv.w };
        #pragma unroll
        for (int u = 0; u < 4; u++)
            #pragma unroll
            for (int v = 0; v < 4; v++) acc[u][v] += a[u] * bb[v];
    }
    const float4 bo = *(const float4*)(bout + col0 + tc * 4);
    #pragma unroll
    for (int u = 0; u < 4; u++) {
        float4 r4 = make_float4(acc[u][0] + bo.x, acc[u][1] + bo.y,
                                acc[u][2] + bo.z, acc[u][3] + bo.w);
        *(float4*)(y + (size_t)(row0 + tr*4 + u) * F_ + col0 + tc * 4) = r4;
    }
}

// ---- launch ------------------------------------------------------------
extern "C" void kernel_launch(void* const* d_in, const int* in_sizes, int n_in,
                              void* d_out, int out_size, void* d_ws, size_t ws_size,
                              hipStream_t stream)
{
    const float* x      = (const float*)d_in[0];
    const float* action = (const float*)d_in[1];
    const float* mask   = (const float*)d_in[2];
    const float* carry  = (const float*)d_in[3];
    const float* Wq     = (const float*)d_in[4];
    const float* Wk     = (const float*)d_in[5];
    const float* Wv     = (const float*)d_in[6];
    const float* Wbeta  = (const float*)d_in[7];
    const float* Walpha = (const float*)d_in[8];
    const float* Wku    = (const float*)d_in[9];
    const float* Wvu    = (const float*)d_in[10];
    const float* Wgamma = (const float*)d_in[11];
    const float* rms_s  = (const float*)d_in[12];
    const float* Wout   = (const float*)d_in[13];
    const float* bout   = (const float*)d_in[14];

    float* carry_out = (float*)d_out;                       // B*H*D*D = 32768
    float* y         = (float*)d_out + (size_t)BH_ * D_ * D_;

    // workspace: ~61 MB of fp32 scratch
    float* ws = (float*)d_ws;
    float* qb     = ws; ws += (size_t)ROWS_ * HID_;
    float* kb     = ws; ws += (size_t)ROWS_ * HID_;
    float* vb     = ws; ws += (size_t)ROWS_ * HID_;
    float* kub    = ws; ws += (size_t)ROWS_ * HID_;
    float* vub    = ws; ws += (size_t)ROWS_ * HID_;
    float* betab  = ws; ws += (size_t)ROWS_ * H_;
    float* alphab = ws; ws += (size_t)ROWS_ * H_;
    float* gammab = ws; ws += (size_t)ROWS_ * H_;
    float* outpre = ws; ws += (size_t)ROWS_ * HID_;
    float* cumA   = ws; ws += (size_t)BH_ * NC_ * D_ * D_;
    float* cumB   = ws; ws += (size_t)BH_ * NC_ * D_ * D_;
    float* Sst    = ws; ws += (size_t)BH_ * NC_ * D_ * D_;

    gemm_x_kernel<<<dim3(ROWS_/128, HID_/128, 3), 256, 0, stream>>>(
        x, Wq, Wk, Wv, qb, kb, vb);
    gemm_ba_kernel<<<dim3(ROWS_/16), 256, 0, stream>>>(x, Wbeta, Walpha, betab, alphab);
    gemm_act_kernel<<<dim3((ROWS_*520 + 255)/256), 256, 0, stream>>>(
        action, Wku, Wvu, Wgamma, kub, vub, gammab);
    silu_norm_kernel<<<dim3(ROWS_*H_/8), 256, 0, stream>>>(qb, kb, kub);
    scan_pass1<<<dim3(BH_, NC_), 64, 0, stream>>>(
        kb, vb, kub, vub, betab, alphab, gammab, mask, cumA, cumB);
    scan_pass2<<<dim3(BH_), 1024, 0, stream>>>(carry, cumA, cumB, Sst, carry_out);
    scan_pass3<<<dim3(BH_, NC_), 64, 0, stream>>>(
        qb, kb, vb, kub, vub, betab, alphab, gammab, mask, Sst, outpre);
    out_kernel<<<dim3(ROWS_/32, F_/128), 256, 0, stream>>>(
        outpre, rms_s, Wout, bout, y);
}

// Round 3
// 350.301 us; speedup vs baseline: 1.2337x; 1.2337x over previous
//
#include <hip/hip_runtime.h>
#include <math.h>

// ---- problem constants -------------------------------------------------
constexpr int B_    = 4;
constexpr int S_    = 2048;
constexpr int F_    = 512;     // IN_FEATURES
constexpr int H_    = 8;       // NUM_HEADS
constexpr int D_    = 32;      // HEAD_DIM
constexpr int HID_  = 256;     // H_*D_
constexpr int NA_   = 16;      // NUM_ACTIONS
constexpr int ROWS_ = B_ * S_; // 8192
constexpr int CHUNK_= 64;      // steps per scan chunk
constexpr int NC_   = S_ / CHUNK_;  // 32 chunks
constexpr int T_    = 16;      // timesteps staged per LDS tile
constexpr int NT_   = CHUNK_ / T_;  // 4 tiles per chunk
constexpr int BH_   = B_ * H_;      // 32

typedef __attribute__((ext_vector_type(8))) short short8;
typedef __attribute__((ext_vector_type(4))) float f32x4;
typedef unsigned short u16;

__device__ __forceinline__ float sigmoidf_(float x) { return 1.0f / (1.0f + expf(-x)); }

// fp32 -> bf16 (RNE) and back, plus hi/lo split (a ~= hi + lo, err ~2^-17 rel)
__device__ __forceinline__ u16 f2bf(float f) {
    unsigned u = __float_as_uint(f);
    return (u16)((u + 0x7FFF + ((u >> 16) & 1)) >> 16);
}
__device__ __forceinline__ float bf2f(u16 h) {
    return __uint_as_float(((unsigned)h) << 16);
}
__device__ __forceinline__ void bfsplit(float x, u16& hi, u16& lo) {
    hi = f2bf(x);
    lo = f2bf(x - bf2f(hi));
}

// XOR swizzle within a 64-byte LDS row: spreads 16B fragment chunks across
// the 8 16B-slots so wave64 ds_read_b128 is <=2-way (free) conflicted.
__device__ __forceinline__ unsigned swz(unsigned r, unsigned cbyte) {
    return cbyte ^ (((r >> 1) & 3) << 4);
}

// ---- K0a: convert x (f32) -> xh, xl bf16 (row-major 8192x512) ----------
__global__ __launch_bounds__(256) void conv_x_kernel(
    const float* __restrict__ x, u16* __restrict__ xh, u16* __restrict__ xl)
{
    const int idx = blockIdx.x * 256 + threadIdx.x;       // one float4 each
    const float4 v = ((const float4*)x)[idx];
    ushort4 h, l;
    bfsplit(v.x, h.x, l.x); bfsplit(v.y, h.y, l.y);
    bfsplit(v.z, h.z, l.z); bfsplit(v.w, h.w, l.w);
    ((ushort4*)xh)[idx] = h;
    ((ushort4*)xl)[idx] = l;
}

// ---- K0b: transpose + convert weights to [N][K] bf16 hi/lo -------------
// z=0..2: Wq/Wk/Wv (512x256) -> wt + z*256*512  (dst [256][512])
// z=3:    Wout     (256x512) -> wot             (dst [512][256])
__global__ __launch_bounds__(256) void conv_w_kernel(
    const float* __restrict__ Wq, const float* __restrict__ Wk,
    const float* __restrict__ Wv, const float* __restrict__ Wout,
    u16* __restrict__ wth, u16* __restrict__ wtl,
    u16* __restrict__ woth, u16* __restrict__ wotl)
{
    const int z = blockIdx.z;
    const float* src; u16 *dh, *dl; int R, C;
    if (z < 3) {
        src = (z == 0) ? Wq : (z == 1) ? Wk : Wv;
        R = 512; C = 256;
        dh = wth + (size_t)z * 256 * 512; dl = wtl + (size_t)z * 256 * 512;
    } else {
        src = Wout; R = 256; C = 512; dh = woth; dl = wotl;
    }
    const int r0 = blockIdx.x * 32, c0 = blockIdx.y * 32;
    if (r0 >= R || c0 >= C) return;
    __shared__ float tile[32][33];
    const int tx = threadIdx.x & 31, ty = threadIdx.x >> 5;   // 32x8
    #pragma unroll
    for (int i = 0; i < 4; i++)
        tile[ty + i * 8][tx] = src[(size_t)(r0 + ty + i * 8) * C + c0 + tx];
    __syncthreads();
    #pragma unroll
    for (int i = 0; i < 4; i++) {
        const float v = tile[tx][ty + i * 8];
        const size_t o = (size_t)(c0 + ty + i * 8) * R + r0 + tx;
        u16 h, l; bfsplit(v, h, l);
        dh[o] = h; dl[o] = l;
    }
}

// ---- K1a: MFMA GEMM  C[8192xN] = A[8192xK] @ Bt[NxK]^T  (bf16x3) -------
// A given as hi/lo bf16 row-major; Bt as hi/lo bf16 [N][K] (pre-transposed).
// Block: 128 threads = 2 waves; tile 128(M) x 64(N); wave tile 64x64 =
// 4x4 fragments of 16x16x32; 3 MFMAs per fragment (hh, hl, lh).
__global__ __launch_bounds__(128) void mfma_gemm_kernel(
    const u16* __restrict__ Ah, const u16* __restrict__ Al,
    const u16* __restrict__ Bth, const u16* __restrict__ Btl,
    float* __restrict__ Cbase, int K, int N,
    int btStride, int cStride, const float* __restrict__ bias)
{
    const u16* bh_p = Bth + (size_t)blockIdx.z * btStride;
    const u16* bl_p = Btl + (size_t)blockIdx.z * btStride;
    float* C = Cbase + (size_t)blockIdx.z * cStride;

    __shared__ u16 lAh[128 * 32], lAl[128 * 32];   // 8 KB each
    __shared__ u16 lBh[64 * 32],  lBl[64 * 32];    // 4 KB each

    const int t    = threadIdx.x;
    const int wave = t >> 6;
    const int lane = t & 63;
    const int lr   = lane & 15;        // row/col within fragment
    const int lk   = lane >> 4;        // k-quad (0..3)
    const int row0 = blockIdx.x * 128;
    const int col0 = blockIdx.y * 64;

    f32x4 acc[4][4];
    #pragma unroll
    for (int i = 0; i < 4; i++)
        #pragma unroll
        for (int j = 0; j < 4; j++) acc[i][j] = (f32x4){0.f, 0.f, 0.f, 0.f};

    for (int k0 = 0; k0 < K; k0 += 32) {
        // stage A tile (128x32) hi+lo: 512 16B-chunks each, 4 per thread
        #pragma unroll
        for (int u = 0; u < 4; u++) {
            const int slot = t + u * 128;
            const int r = slot >> 2, cq = slot & 3;
            const size_t g = (size_t)(row0 + r) * K + k0 + cq * 8;
            const unsigned bo = r * 64 + swz(r, cq * 16);
            *(uint4*)((char*)lAh + bo) = *(const uint4*)(Ah + g);
            *(uint4*)((char*)lAl + bo) = *(const uint4*)(Al + g);
        }
        // stage B tile (64x32) hi+lo: 256 chunks each, 2 per thread
        #pragma unroll
        for (int u = 0; u < 2; u++) {
            const int slot = t + u * 128;
            const int r = slot >> 2, cq = slot & 3;
            const size_t g = (size_t)(col0 + r) * K + k0 + cq * 8;
            const unsigned bo = r * 64 + swz(r, cq * 16);
            *(uint4*)((char*)lBh + bo) = *(const uint4*)(bh_p + g);
            *(uint4*)((char*)lBl + bo) = *(const uint4*)(bl_p + g);
        }
        __syncthreads();

        short8 ah[4], al[4];
        #pragma unroll
        for (int tm = 0; tm < 4; tm++) {
            const int r = wave * 64 + tm * 16 + lr;
            const unsigned bo = r * 64 + swz(r, lk * 16);
            ah[tm] = *(const short8*)((const char*)lAh + bo);
            al[tm] = *(const short8*)((const char*)lAl + bo);
        }
        #pragma unroll
        for (int tn = 0; tn < 4; tn++) {
            const int r = tn * 16 + lr;
            const unsigned bo = r * 64 + swz(r, lk * 16);
            const short8 bh = *(const short8*)((const char*)lBh + bo);
            const short8 bl = *(const short8*)((const char*)lBl + bo);
            #pragma unroll
            for (int tm = 0; tm < 4; tm++) {
                acc[tm][tn] = __builtin_amdgcn_mfma_f32_16x16x32_bf16(
                    ah[tm], bh, acc[tm][tn], 0, 0, 0);
                acc[tm][tn] = __builtin_amdgcn_mfma_f32_16x16x32_bf16(
                    ah[tm], bl, acc[tm][tn], 0, 0, 0);
                acc[tm][tn] = __builtin_amdgcn_mfma_f32_16x16x32_bf16(
                    al[tm], bh, acc[tm][tn], 0, 0, 0);
            }
        }
        __syncthreads();
    }

    // epilogue: C/D layout col=lane&15, row=(lane>>4)*4+v  (m89-verified)
    #pragma unroll
    for (int tm = 0; tm < 4; tm++) {
        #pragma unroll
        for (int tn = 0; tn < 4; tn++) {
            const int col = col0 + tn * 16 + lr;
            const float b = bias ? bias[col] : 0.0f;
            #pragma unroll
            for (int v = 0; v < 4; v++) {
                const int row = row0 + wave * 64 + tm * 16 + lk * 4 + v;
                C[(size_t)row * N + col] = acc[tm][tn][v] + b;
            }
        }
    }
}

// ---- K1b: beta/alpha projection (8192x512 @ 512x8, x2) + sigmoid -------
__global__ __launch_bounds__(256) void gemm_ba_kernel(
    const float* __restrict__ x, const float* __restrict__ Wb, const float* __restrict__ Wa,
    float* __restrict__ betab, float* __restrict__ alphab)
{
    __shared__ float xs[16][F_];     // 32 KB
    const int t = threadIdx.x;
    const int row0 = blockIdx.x * 16;
    #pragma unroll
    for (int i = 0; i < 8; i++) {
        int slot = t + i * 256;              // 2048 float4 slots
        int r = slot >> 7, kq = slot & 127;
        *(float4*)&xs[r][kq*4] = *(const float4*)(x + (size_t)(row0 + r) * F_ + kq * 4);
    }
    __syncthreads();
    const int j = t & 15, mloc = t >> 4;
    const float* W = (j < 8) ? Wb : Wa;
    const int jc = j & 7;
    float acc = 0.0f;
    #pragma unroll 4
    for (int kk = 0; kk < F_; kk++) acc += xs[mloc][kk] * W[kk * 8 + jc];
    float r = sigmoidf_(acc);
    if (j < 8) betab[(row0 + mloc) * 8 + jc] = r;
    else       alphab[(row0 + mloc) * 8 + jc] = r;
}

// ---- K1c: action projections (K=16) ku/vu/gamma ------------------------
__global__ __launch_bounds__(256) void gemm_act_kernel(
    const float* __restrict__ act, const float* __restrict__ Wku,
    const float* __restrict__ Wvu, const float* __restrict__ Wg,
    float* __restrict__ ku, float* __restrict__ vu, float* __restrict__ bg)
{
    int o = blockIdx.x * 256 + threadIdx.x;
    const int total = ROWS_ * 520;           // 256 + 256 + 8
    if (o >= total) return;
    int row = o / 520;
    int col = o - row * 520;
    const float* a = act + (size_t)row * NA_;
    float acc = 0.0f;
    if (col < 256) {
        #pragma unroll
        for (int kk = 0; kk < NA_; kk++) acc += a[kk] * Wku[kk * HID_ + col];
        ku[(size_t)row * HID_ + col] = acc;
    } else if (col < 512) {
        int c = col - 256;
        #pragma unroll
        for (int kk = 0; kk < NA_; kk++) acc += a[kk] * Wvu[kk * HID_ + c];
        vu[(size_t)row * HID_ + c] = acc;
    } else {
        int c = col - 512;
        #pragma unroll
        for (int kk = 0; kk < NA_; kk++) acc += a[kk] * Wg[kk * H_ + c];
        bg[(size_t)row * H_ + c] = sigmoidf_(acc);
    }
}

// ---- K2: silu + l2norm (per 32-elem head group) for q, k, ku, in place -
__global__ __launch_bounds__(256) void silu_norm_kernel(
    float* __restrict__ q, float* __restrict__ k, float* __restrict__ ku)
{
    const int t = threadIdx.x;
    const int d = t & 31;
    const size_t g = (size_t)blockIdx.x * 8 + (t >> 5);   // head-group id
    const size_t idx = g * 32 + d;
    float* bufs[3] = { q, k, ku };
    #pragma unroll
    for (int a = 0; a < 3; a++) {
        float x = bufs[a][idx];
        float v = x * (1.0f / (1.0f + expf(-x)));
        float ss = v * v;
        ss += __shfl_xor(ss, 1);  ss += __shfl_xor(ss, 2);  ss += __shfl_xor(ss, 4);
        ss += __shfl_xor(ss, 8);  ss += __shfl_xor(ss, 16);
        bufs[a][idx] = v * rsqrtf(ss + 1e-6f);
    }
}

// ---- K3a: per-chunk (cumA, cumB) via rank-1 recurrences ----------------
__global__ __launch_bounds__(64) void scan_pass1(
    const float* __restrict__ kbuf, const float* __restrict__ vbuf,
    const float* __restrict__ kubuf, const float* __restrict__ vubuf,
    const float* __restrict__ betab, const float* __restrict__ alphab,
    const float* __restrict__ gammab, const float* __restrict__ mask,
    float* __restrict__ cumA, float* __restrict__ cumB)
{
    const int bh = blockIdx.x;     // 0..31
    const int c  = blockIdx.y;     // 0..NC_-1
    const int b  = bh >> 3, h = bh & 7;
    const int t  = threadIdx.x;
    const int i  = t >> 1;
    const int j0 = (t & 1) * 16;
    __shared__ float lk [T_][32];
    __shared__ float lv [T_][32];
    __shared__ float lku[T_][32];
    __shared__ float lvu[T_][32];
    __shared__ float lsc[T_][4];   // 0:beta 1:alpha*(1-mask) 2:gamma

    float M[16], Cc[16];
    #pragma unroll
    for (int jj = 0; jj < 16; jj++) { M[jj] = (i == j0 + jj) ? 1.0f : 0.0f; Cc[jj] = 0.0f; }

    auto stage = [&](int tile, float4* pk, float4* pv, float4* pku, float4* pvu,
                     float& sb, float& sa, float& sg) {
        const int row_base = b * S_ + c * CHUNK_ + tile * T_;
        #pragma unroll
        for (int u = 0; u < 2; u++) {
            int slot = t + u * 64;           // 128 float4 slots: 16 rows x 8 quads
            int r = slot >> 3, q = slot & 7;
            const size_t gb = (size_t)(row_base + r) * HID_ + h * D_ + q * 4;
            pk[u]  = *(const float4*)(kbuf  + gb);
            pv[u]  = *(const float4*)(vbuf  + gb);
            pku[u] = *(const float4*)(kubuf + gb);
            pvu[u] = *(const float4*)(vubuf + gb);
        }
        const int r = t & 15;
        const int rowi = row_base + r;
        if (t < 16)       sb = betab [(size_t)rowi * H_ + h];
        else if (t < 32)  sa = alphab[(size_t)rowi * H_ + h] * (1.0f - mask[rowi]);
        else if (t < 48)  sg = gammab[(size_t)rowi * H_ + h];
    };
    auto commit = [&](float4* pk, float4* pv, float4* pku, float4* pvu,
                      float sb, float sa, float sg) {
        #pragma unroll
        for (int u = 0; u < 2; u++) {
            int slot = t + u * 64;
            int r = slot >> 3, q = slot & 7;
            *(float4*)&lk [r][q*4] = pk[u];
            *(float4*)&lv [r][q*4] = pv[u];
            *(float4*)&lku[r][q*4] = pku[u];
            *(float4*)&lvu[r][q*4] = pvu[u];
        }
        const int r = t & 15;
        if (t < 16)       lsc[r][0] = sb;
        else if (t < 32)  lsc[r][1] = sa;
        else if (t < 48)  lsc[r][2] = sg;
    };

    float4 pk[2], pv[2], pku[2], pvu[2]; float sb = 0, sa = 0, sg = 0;
    stage(0, pk, pv, pku, pvu, sb, sa, sg);

    for (int tile = 0; tile < NT_; ++tile) {
        commit(pk, pv, pku, pvu, sb, sa, sg);
        __syncthreads();
        float4 nk[2], nv[2], nku[2], nvu[2]; float nb = 0, na = 0, ng = 0;
        if (tile + 1 < NT_) stage(tile + 1, nk, nv, nku, nvu, nb, na, ng);

        #pragma unroll
        for (int sl = 0; sl < T_; sl++) {
            const float vi  = lv [sl][i];
            const float vui = lvu[sl][i];
            const float bet = lsc[sl][0];
            const float a   = lsc[sl][1];
            const float bgm = lsc[sl][2];
            float kj[16], kuj[16];
            #pragma unroll
            for (int jj = 0; jj < 16; jj++) { kj[jj] = lk[sl][j0 + jj]; kuj[jj] = lku[sl][j0 + jj]; }
            float pd = 0.0f;
            #pragma unroll
            for (int jj = 0; jj < 16; jj++) pd += kuj[jj] * kj[jj];
            const float duk = pd + __shfl_xor(pd, 1);
            float mk = 0.0f, ck = 0.0f;
            #pragma unroll
            for (int jj = 0; jj < 16; jj++) { mk += M[jj] * kj[jj]; ck += Cc[jj] * kj[jj]; }
            mk += __shfl_xor(mk, 1);
            ck += __shfl_xor(ck, 1);
            const float abk_m   = a * bet * mk;
            const float ck_coef = bet * vi - a * bet * ck;
            const float wu      = bgm * vui;
            const float bduk    = bet * duk;
            #pragma unroll
            for (int jj = 0; jj < 16; jj++) {
                const float kv = kj[jj];
                const float w  = kuj[jj] - bduk * kv;         // (ku^T @ delta)[j]
                M[jj]  = a * M[jj]  - abk_m   * kv;           // M @ decay
                Cc[jj] = a * Cc[jj] + ck_coef * kv + wu * w;  // C @ decay + update
            }
        }
        __syncthreads();
        #pragma unroll
        for (int u = 0; u < 2; u++) { pk[u] = nk[u]; pv[u] = nv[u]; pku[u] = nku[u]; pvu[u] = nvu[u]; }
        sb = nb; sa = na; sg = ng;
    }
    const size_t ofs = ((size_t)(bh * NC_ + c)) * 1024 + (size_t)i * 32 + j0;
    #pragma unroll
    for (int u = 0; u < 4; u++) {
        *(float4*)(cumA + ofs + u*4) = make_float4(M[u*4],  M[u*4+1],  M[u*4+2],  M[u*4+3]);
        *(float4*)(cumB + ofs + u*4) = make_float4(Cc[u*4], Cc[u*4+1], Cc[u*4+2], Cc[u*4+3]);
    }
}

// ---- K3b: sequential chunk composition; emits Sstart per chunk + carry --
__global__ __launch_bounds__(1024) void scan_pass2(
    const float* __restrict__ carry, const float* __restrict__ cumA,
    const float* __restrict__ cumB, float* __restrict__ Sstart,
    float* __restrict__ carry_out)
{
    const int bh = blockIdx.x;
    const int t  = threadIdx.x;
    const int i  = t >> 5;
    const int j  = t & 31;
    __shared__ float Ssh[32][33];
    __shared__ float Ash[32][33];
    const size_t idx = (size_t)i * 32 + j;
    float Sv = carry[(size_t)bh * 1024 + idx];

    float Anext = cumA[((size_t)(bh * NC_)) * 1024 + idx];
    float Bnext = cumB[((size_t)(bh * NC_)) * 1024 + idx];
    for (int c = 0; c < NC_; c++) {
        const size_t ofs = ((size_t)(bh * NC_ + c)) * 1024;
        Sstart[ofs + idx] = Sv;
        Ssh[i][j] = Sv;
        Ash[i][j] = Anext;
        const float Bcur = Bnext;
        __syncthreads();
        if (c + 1 < NC_) {                 // issue next chunk's loads early
            const size_t ofs2 = ofs + 1024;
            Anext = cumA[ofs2 + idx];
            Bnext = cumB[ofs2 + idx];
        }
        float acc = Bcur;
        #pragma unroll 8
        for (int m = 0; m < 32; m++) acc += Ssh[i][m] * Ash[m][j];
        __syncthreads();
        Sv = acc;
    }
    carry_out[(size_t)bh * 1024 + idx] = Sv;
}

// ---- K3c: replay each chunk from Sstart, emit out = S_new . q ----------
__global__ __launch_bounds__(64) void scan_pass3(
    const float* __restrict__ qbuf, const float* __restrict__ kbuf,
    const float* __restrict__ vbuf, const float* __restrict__ kubuf,
    const float* __restrict__ vubuf, const float* __restrict__ betab,
    const float* __restrict__ alphab, const float* __restrict__ gammab,
    const float* __restrict__ mask, const float* __restrict__ Sstart,
    float* __restrict__ outpre)
{
    const int bh = blockIdx.x, c = blockIdx.y;
    const int b  = bh >> 3, h = bh & 7;
    const int t  = threadIdx.x;
    const int i  = t >> 1;
    const int j0 = (t & 1) * 16;
    __shared__ float lk [T_][32];
    __shared__ float lq [T_][32];
    __shared__ float lv [T_][32];
    __shared__ float lku[T_][32];
    __shared__ float lvu[T_][32];
    __shared__ float lsc[T_][4];

    float Sv[16];
    const size_t sofs = ((size_t)(bh * NC_ + c)) * 1024 + (size_t)i * 32 + j0;
    #pragma unroll
    for (int u = 0; u < 4; u++) {
        float4 s4 = *(const float4*)(Sstart + sofs + u*4);
        Sv[u*4] = s4.x; Sv[u*4+1] = s4.y; Sv[u*4+2] = s4.z; Sv[u*4+3] = s4.w;
    }

    auto stage = [&](int tile, float4* pk, float4* pq, float4* pv, float4* pku, float4* pvu,
                     float& sb, float& sa, float& sg) {
        const int row_base = b * S_ + c * CHUNK_ + tile * T_;
        #pragma unroll
        for (int u = 0; u < 2; u++) {
            int slot = t + u * 64;
            int r = slot >> 3, q = slot & 7;
            const size_t gb = (size_t)(row_base + r) * HID_ + h * D_ + q * 4;
            pk[u]  = *(const float4*)(kbuf  + gb);
            pq[u]  = *(const float4*)(qbuf  + gb);
            pv[u]  = *(const float4*)(vbuf  + gb);
            pku[u] = *(const float4*)(kubuf + gb);
            pvu[u] = *(const float4*)(vubuf + gb);
        }
        const int r = t & 15;
        const int rowi = row_base + r;
        if (t < 16)       sb = betab [(size_t)rowi * H_ + h];
        else if (t < 32)  sa = alphab[(size_t)rowi * H_ + h] * (1.0f - mask[rowi]);
        else if (t < 48)  sg = gammab[(size_t)rowi * H_ + h];
    };
    auto commit = [&](float4* pk, float4* pq, float4* pv, float4* pku, float4* pvu,
                      float sb, float sa, float sg) {
        #pragma unroll
        for (int u = 0; u < 2; u++) {
            int slot = t + u * 64;
            int r = slot >> 3, q = slot & 7;
            *(float4*)&lk [r][q*4] = pk[u];
            *(float4*)&lq [r][q*4] = pq[u];
            *(float4*)&lv [r][q*4] = pv[u];
            *(float4*)&lku[r][q*4] = pku[u];
            *(float4*)&lvu[r][q*4] = pvu[u];
        }
        const int r = t & 15;
        if (t < 16)       lsc[r][0] = sb;
        else if (t < 32)  lsc[r][1] = sa;
        else if (t < 48)  lsc[r][2] = sg;
    };

    float4 pk[2], pq[2], pv[2], pku[2], pvu[2]; float sb = 0, sa = 0, sg = 0;
    stage(0, pk, pq, pv, pku, pvu, sb, sa, sg);

    for (int tile = 0; tile < NT_; ++tile) {
        commit(pk, pq, pv, pku, pvu, sb, sa, sg);
        __syncthreads();
        float4 nk[2], nq[2], nv[2], nku[2], nvu[2]; float nb = 0, na = 0, ng = 0;
        if (tile + 1 < NT_) stage(tile + 1, nk, nq, nv, nku, nvu, nb, na, ng);

        const int row_base = b * S_ + c * CHUNK_ + tile * T_;
        #pragma unroll
        for (int sl = 0; sl < T_; sl++) {
            const float vi  = lv [sl][i];
            const float vui = lvu[sl][i];
            const float bet = lsc[sl][0];
            const float a   = lsc[sl][1];
            const float bgm = lsc[sl][2];
            float kj[16], kuj[16], qj[16];
            #pragma unroll
            for (int jj = 0; jj < 16; jj++) {
                kj[jj] = lk[sl][j0 + jj]; kuj[jj] = lku[sl][j0 + jj]; qj[jj] = lq[sl][j0 + jj];
            }
            float pd = 0.0f;
            #pragma unroll
            for (int jj = 0; jj < 16; jj++) pd += kuj[jj] * kj[jj];
            const float duk = pd + __shfl_xor(pd, 1);
            float sk = 0.0f;
            #pragma unroll
            for (int jj = 0; jj < 16; jj++) sk += Sv[jj] * kj[jj];
            sk += __shfl_xor(sk, 1);
            const float coef_k = bet * vi - a * bet * sk;
            const float wu     = bgm * vui;
            const float bduk   = bet * duk;
            float op = 0.0f;
            #pragma unroll
            for (int jj = 0; jj < 16; jj++) {
                const float kv = kj[jj];
                const float w  = kuj[jj] - bduk * kv;
                Sv[jj] = a * Sv[jj] + coef_k * kv + wu * w;
                op += Sv[jj] * qj[jj];
            }
            op += __shfl_xor(op, 1);
            if ((t & 1) == 0)
                outpre[(size_t)(row_base + sl) * HID_ + h * D_ + i] = op;
        }
        __syncthreads();
        #pragma unroll
        for (int u = 0; u < 2; u++) {
            pk[u] = nk[u]; pq[u] = nq[u]; pv[u] = nv[u]; pku[u] = nku[u]; pvu[u] = nvu[u];
        }
        sb = nb; sa = na; sg = ng;
    }
}

// ---- K4a: RMS norm + rms_scale -> bf16 hi/lo (one wave per row) --------
__global__ __launch_bounds__(256) void rms_conv_kernel(
    const float* __restrict__ outpre, const float* __restrict__ rms_scale,
    u16* __restrict__ onh, u16* __restrict__ onl)
{
    const int t = threadIdx.x;
    const int lane = t & 63;
    const int row = blockIdx.x * 4 + (t >> 6);
    const float4 v = ((const float4*)(outpre + (size_t)row * HID_))[lane];
    float ss = v.x*v.x + v.y*v.y + v.z*v.z + v.w*v.w;
    ss += __shfl_xor(ss, 1);  ss += __shfl_xor(ss, 2);  ss += __shfl_xor(ss, 4);
    ss += __shfl_xor(ss, 8);  ss += __shfl_xor(ss, 16); ss += __shfl_xor(ss, 32);
    const float rinv = rsqrtf(ss * (1.0f / HID_) + 1e-6f);
    const float4 sc = ((const float4*)rms_scale)[lane];
    ushort4 h, l;
    bfsplit(v.x * rinv * sc.x, h.x, l.x);
    bfsplit(v.y * rinv * sc.y, h.y, l.y);
    bfsplit(v.z * rinv * sc.z, h.z, l.z);
    bfsplit(v.w * rinv * sc.w, h.w, l.w);
    ((ushort4*)(onh + (size_t)row * HID_))[lane] = h;
    ((ushort4*)(onl + (size_t)row * HID_))[lane] = l;
}

// ---- launch ------------------------------------------------------------
extern "C" void kernel_launch(void* const* d_in, const int* in_sizes, int n_in,
                              void* d_out, int out_size, void* d_ws, size_t ws_size,
                              hipStream_t stream)
{
    const float* x      = (const float*)d_in[0];
    const float* action = (const float*)d_in[1];
    const float* mask   = (const float*)d_in[2];
    const float* carry  = (const float*)d_in[3];
    const float* Wq     = (const float*)d_in[4];
    const float* Wk     = (const float*)d_in[5];
    const float* Wv     = (const float*)d_in[6];
    const float* Wbeta  = (const float*)d_in[7];
    const float* Walpha = (const float*)d_in[8];
    const float* Wku    = (const float*)d_in[9];
    const float* Wvu    = (const float*)d_in[10];
    const float* Wgamma = (const float*)d_in[11];
    const float* rms_s  = (const float*)d_in[12];
    const float* Wout   = (const float*)d_in[13];
    const float* bout   = (const float*)d_in[14];

    float* carry_out = (float*)d_out;                       // B*H*D*D = 32768
    float* y         = (float*)d_out + (size_t)BH_ * D_ * D_;

    float* ws = (float*)d_ws;
    float* qb     = ws; ws += (size_t)ROWS_ * HID_;    // qb,kb,vb contiguous
    float* kb     = ws; ws += (size_t)ROWS_ * HID_;
    float* vb     = ws; ws += (size_t)ROWS_ * HID_;
    float* kub    = ws; ws += (size_t)ROWS_ * HID_;
    float* vub    = ws; ws += (size_t)ROWS_ * HID_;
    float* betab  = ws; ws += (size_t)ROWS_ * H_;
    float* alphab = ws; ws += (size_t)ROWS_ * H_;
    float* gammab = ws; ws += (size_t)ROWS_ * H_;
    float* cumA   = ws; ws += (size_t)BH_ * NC_ * D_ * D_;
    float* cumB   = ws; ws += (size_t)BH_ * NC_ * D_ * D_;
    float* Sst    = ws; ws += (size_t)BH_ * NC_ * D_ * D_;
    u16* xh       = (u16*)ws; ws += (size_t)ROWS_ * F_ / 2;   // bf16 halves
    u16* xl       = (u16*)ws; ws += (size_t)ROWS_ * F_ / 2;
    u16* wth      = (u16*)ws; ws += (size_t)3 * HID_ * F_ / 2;
    u16* wtl      = (u16*)ws; ws += (size_t)3 * HID_ * F_ / 2;
    u16* woth     = (u16*)ws; ws += (size_t)F_ * HID_ / 2;
    u16* wotl     = (u16*)ws; ws += (size_t)F_ * HID_ / 2;
    float* outpre = ws; ws += (size_t)ROWS_ * HID_;
    // onh/onl alias qb (free after scan_pass3; each 4 MB, qb is 8 MB)
    u16* onh = (u16*)qb;
    u16* onl = (u16*)qb + (size_t)ROWS_ * HID_;

    conv_x_kernel<<<dim3(ROWS_ * F_ / 4 / 256), 256, 0, stream>>>(x, xh, xl);
    conv_w_kernel<<<dim3(16, 16, 4), 256, 0, stream>>>(
        Wq, Wk, Wv, Wout, wth, wtl, woth, wotl);
    // q/k/v projections: A=x(hi/lo) K=512, Bt=wt N=256, out -> qb/kb/vb
    mfma_gemm_kernel<<<dim3(ROWS_/128, HID_/64, 3), 128, 0, stream>>>(
        xh, xl, wth, wtl, qb, F_, HID_, HID_ * F_, ROWS_ * HID_, nullptr);
    gemm_ba_kernel<<<dim3(ROWS_/16), 256, 0, stream>>>(x, Wbeta, Walpha, betab, alphab);
    gemm_act_kernel<<<dim3((ROWS_*520 + 255)/256), 256, 0, stream>>>(
        action, Wku, Wvu, Wgamma, kub, vub, gammab);
    silu_norm_kernel<<<dim3(ROWS_*H_/8), 256, 0, stream>>>(qb, kb, kub);
    scan_pass1<<<dim3(BH_, NC_), 64, 0, stream>>>(
        kb, vb, kub, vub, betab, alphab, gammab, mask, cumA, cumB);
    scan_pass2<<<dim3(BH_), 1024, 0, stream>>>(carry, cumA, cumB, Sst, carry_out);
    scan_pass3<<<dim3(BH_, NC_), 64, 0, stream>>>(
        qb, kb, vb, kub, vub, betab, alphab, gammab, mask, Sst, outpre);
    rms_conv_kernel<<<dim3(ROWS_/4), 256, 0, stream>>>(outpre, rms_s, onh, onl);
    // output projection: A=on(hi/lo) K=256, Bt=wot N=512, +bias -> y
    mfma_gemm_kernel<<<dim3(ROWS_/128, F_/64, 1), 128, 0, stream>>>(
        onh, onl, woth, wotl, y, HID_, F_, 0, 0, bout);
}

// Round 4
// 338.185 us; speedup vs baseline: 1.2779x; 1.0358x over previous
//
#include <hip/hip_runtime.h>
#include <math.h>

// ---- problem constants -------------------------------------------------
constexpr int B_    = 4;
constexpr int S_    = 2048;
constexpr int F_    = 512;     // IN_FEATURES
constexpr int H_    = 8;       // NUM_HEADS
constexpr int D_    = 32;      // HEAD_DIM
constexpr int HID_  = 256;     // H_*D_
constexpr int NA_   = 16;      // NUM_ACTIONS
constexpr int ROWS_ = B_ * S_; // 8192
constexpr int CHUNK_= 64;      // steps per scan chunk
constexpr int NC_   = S_ / CHUNK_;  // 32 chunks
constexpr int T_    = 16;      // timesteps staged per LDS tile
constexpr int NT_   = CHUNK_ / T_;  // 4 tiles per chunk
constexpr int BH_   = B_ * H_;      // 32

typedef __attribute__((ext_vector_type(8))) short short8;
typedef __attribute__((ext_vector_type(4))) float f32x4;
typedef unsigned short u16;

__device__ __forceinline__ float sigmoidf_(float x) { return 1.0f / (1.0f + expf(-x)); }

// fp32 -> bf16 (RNE) and back, plus hi/lo split (a ~= hi + lo, err ~2^-17 rel)
__device__ __forceinline__ u16 f2bf(float f) {
    unsigned u = __float_as_uint(f);
    return (u16)((u + 0x7FFF + ((u >> 16) & 1)) >> 16);
}
__device__ __forceinline__ float bf2f(u16 h) {
    return __uint_as_float(((unsigned)h) << 16);
}
__device__ __forceinline__ void bfsplit(float x, u16& hi, u16& lo) {
    hi = f2bf(x);
    lo = f2bf(x - bf2f(hi));
}

// XOR swizzle within a 64-byte LDS row
__device__ __forceinline__ unsigned swz(unsigned r, unsigned cbyte) {
    return cbyte ^ (((r >> 1) & 3) << 4);
}

// ---- K0a: convert x (f32) -> xh, xl bf16 (row-major 8192x512) ----------
__global__ __launch_bounds__(256) void conv_x_kernel(
    const float* __restrict__ x, u16* __restrict__ xh, u16* __restrict__ xl)
{
    const int idx = blockIdx.x * 256 + threadIdx.x;       // one float4 each
    const float4 v = ((const float4*)x)[idx];
    ushort4 h, l;
    bfsplit(v.x, h.x, l.x); bfsplit(v.y, h.y, l.y);
    bfsplit(v.z, h.z, l.z); bfsplit(v.w, h.w, l.w);
    ((ushort4*)xh)[idx] = h;
    ((ushort4*)xl)[idx] = l;
}

// ---- K0b: transpose + convert weights to [N][K] bf16 hi/lo -------------
__global__ __launch_bounds__(256) void conv_w_kernel(
    const float* __restrict__ Wq, const float* __restrict__ Wk,
    const float* __restrict__ Wv, const float* __restrict__ Wout,
    u16* __restrict__ wth, u16* __restrict__ wtl,
    u16* __restrict__ woth, u16* __restrict__ wotl)
{
    const int z = blockIdx.z;
    const float* src; u16 *dh, *dl; int R, C;
    if (z < 3) {
        src = (z == 0) ? Wq : (z == 1) ? Wk : Wv;
        R = 512; C = 256;
        dh = wth + (size_t)z * 256 * 512; dl = wtl + (size_t)z * 256 * 512;
    } else {
        src = Wout; R = 256; C = 512; dh = woth; dl = wotl;
    }
    const int r0 = blockIdx.x * 32, c0 = blockIdx.y * 32;
    if (r0 >= R || c0 >= C) return;
    __shared__ float tile[32][33];
    const int tx = threadIdx.x & 31, ty = threadIdx.x >> 5;   // 32x8
    #pragma unroll
    for (int i = 0; i < 4; i++)
        tile[ty + i * 8][tx] = src[(size_t)(r0 + ty + i * 8) * C + c0 + tx];
    __syncthreads();
    #pragma unroll
    for (int i = 0; i < 4; i++) {
        const float v = tile[tx][ty + i * 8];
        const size_t o = (size_t)(c0 + ty + i * 8) * R + r0 + tx;
        u16 h, l; bfsplit(v, h, l);
        dh[o] = h; dl[o] = l;
    }
}

// ---- K1a: MFMA GEMM  C[8192xN] = A[8192xK] @ Bt[NxK]^T  (bf16x3) -------
__global__ __launch_bounds__(128) void mfma_gemm_kernel(
    const u16* __restrict__ Ah, const u16* __restrict__ Al,
    const u16* __restrict__ Bth, const u16* __restrict__ Btl,
    float* __restrict__ Cbase, int K, int N,
    int btStride, int cStride, const float* __restrict__ bias)
{
    const u16* bh_p = Bth + (size_t)blockIdx.z * btStride;
    const u16* bl_p = Btl + (size_t)blockIdx.z * btStride;
    float* C = Cbase + (size_t)blockIdx.z * cStride;

    __shared__ u16 lAh[128 * 32], lAl[128 * 32];   // 8 KB each
    __shared__ u16 lBh[64 * 32],  lBl[64 * 32];    // 4 KB each

    const int t    = threadIdx.x;
    const int wave = t >> 6;
    const int lane = t & 63;
    const int lr   = lane & 15;        // row/col within fragment
    const int lk   = lane >> 4;        // k-quad (0..3)
    const int row0 = blockIdx.x * 128;
    const int col0 = blockIdx.y * 64;

    f32x4 acc[4][4];
    #pragma unroll
    for (int i = 0; i < 4; i++)
        #pragma unroll
        for (int j = 0; j < 4; j++) acc[i][j] = (f32x4){0.f, 0.f, 0.f, 0.f};

    for (int k0 = 0; k0 < K; k0 += 32) {
        #pragma unroll
        for (int u = 0; u < 4; u++) {
            const int slot = t + u * 128;
            const int r = slot >> 2, cq = slot & 3;
            const size_t g = (size_t)(row0 + r) * K + k0 + cq * 8;
            const unsigned bo = r * 64 + swz(r, cq * 16);
            *(uint4*)((char*)lAh + bo) = *(const uint4*)(Ah + g);
            *(uint4*)((char*)lAl + bo) = *(const uint4*)(Al + g);
        }
        #pragma unroll
        for (int u = 0; u < 2; u++) {
            const int slot = t + u * 128;
            const int r = slot >> 2, cq = slot & 3;
            const size_t g = (size_t)(col0 + r) * K + k0 + cq * 8;
            const unsigned bo = r * 64 + swz(r, cq * 16);
            *(uint4*)((char*)lBh + bo) = *(const uint4*)(bh_p + g);
            *(uint4*)((char*)lBl + bo) = *(const uint4*)(bl_p + g);
        }
        __syncthreads();

        short8 ah[4], al[4];
        #pragma unroll
        for (int tm = 0; tm < 4; tm++) {
            const int r = wave * 64 + tm * 16 + lr;
            const unsigned bo = r * 64 + swz(r, lk * 16);
            ah[tm] = *(const short8*)((const char*)lAh + bo);
            al[tm] = *(const short8*)((const char*)lAl + bo);
        }
        #pragma unroll
        for (int tn = 0; tn < 4; tn++) {
            const int r = tn * 16 + lr;
            const unsigned bo = r * 64 + swz(r, lk * 16);
            const short8 bh = *(const short8*)((const char*)lBh + bo);
            const short8 bl = *(const short8*)((const char*)lBl + bo);
            #pragma unroll
            for (int tm = 0; tm < 4; tm++) {
                acc[tm][tn] = __builtin_amdgcn_mfma_f32_16x16x32_bf16(
                    ah[tm], bh, acc[tm][tn], 0, 0, 0);
                acc[tm][tn] = __builtin_amdgcn_mfma_f32_16x16x32_bf16(
                    ah[tm], bl, acc[tm][tn], 0, 0, 0);
                acc[tm][tn] = __builtin_amdgcn_mfma_f32_16x16x32_bf16(
                    al[tm], bh, acc[tm][tn], 0, 0, 0);
            }
        }
        __syncthreads();
    }

    #pragma unroll
    for (int tm = 0; tm < 4; tm++) {
        #pragma unroll
        for (int tn = 0; tn < 4; tn++) {
            const int col = col0 + tn * 16 + lr;
            const float b = bias ? bias[col] : 0.0f;
            #pragma unroll
            for (int v = 0; v < 4; v++) {
                const int row = row0 + wave * 64 + tm * 16 + lk * 4 + v;
                C[(size_t)row * N + col] = acc[tm][tn][v] + b;
            }
        }
    }
}

// ---- K1b: beta/alpha projection (8192x512 @ 512x8, x2) + sigmoid -------
__global__ __launch_bounds__(256) void gemm_ba_kernel(
    const float* __restrict__ x, const float* __restrict__ Wb, const float* __restrict__ Wa,
    float* __restrict__ betab, float* __restrict__ alphab)
{
    __shared__ float xs[16][F_];     // 32 KB
    const int t = threadIdx.x;
    const int row0 = blockIdx.x * 16;
    #pragma unroll
    for (int i = 0; i < 8; i++) {
        int slot = t + i * 256;              // 2048 float4 slots
        int r = slot >> 7, kq = slot & 127;
        *(float4*)&xs[r][kq*4] = *(const float4*)(x + (size_t)(row0 + r) * F_ + kq * 4);
    }
    __syncthreads();
    const int j = t & 15, mloc = t >> 4;
    const float* W = (j < 8) ? Wb : Wa;
    const int jc = j & 7;
    float acc = 0.0f;
    #pragma unroll 4
    for (int kk = 0; kk < F_; kk++) acc += xs[mloc][kk] * W[kk * 8 + jc];
    float r = sigmoidf_(acc);
    if (j < 8) betab[(row0 + mloc) * 8 + jc] = r;
    else       alphab[(row0 + mloc) * 8 + jc] = r;
}

// ---- K1c: action projections (K=16) ku/vu/gamma ------------------------
__global__ __launch_bounds__(256) void gemm_act_kernel(
    const float* __restrict__ act, const float* __restrict__ Wku,
    const float* __restrict__ Wvu, const float* __restrict__ Wg,
    float* __restrict__ ku, float* __restrict__ vu, float* __restrict__ bg)
{
    int o = blockIdx.x * 256 + threadIdx.x;
    const int total = ROWS_ * 520;           // 256 + 256 + 8
    if (o >= total) return;
    int row = o / 520;
    int col = o - row * 520;
    const float* a = act + (size_t)row * NA_;
    float acc = 0.0f;
    if (col < 256) {
        #pragma unroll
        for (int kk = 0; kk < NA_; kk++) acc += a[kk] * Wku[kk * HID_ + col];
        ku[(size_t)row * HID_ + col] = acc;
    } else if (col < 512) {
        int c = col - 256;
        #pragma unroll
        for (int kk = 0; kk < NA_; kk++) acc += a[kk] * Wvu[kk * HID_ + c];
        vu[(size_t)row * HID_ + c] = acc;
    } else {
        int c = col - 512;
        #pragma unroll
        for (int kk = 0; kk < NA_; kk++) acc += a[kk] * Wg[kk * H_ + c];
        bg[(size_t)row * H_ + c] = sigmoidf_(acc);
    }
}

// ---- K2: silu + l2norm (per 32-elem head group) for q, k, ku, in place -
__global__ __launch_bounds__(256) void silu_norm_kernel(
    float* __restrict__ q, float* __restrict__ k, float* __restrict__ ku)
{
    const int t = threadIdx.x;
    const int d = t & 31;
    const size_t g = (size_t)blockIdx.x * 8 + (t >> 5);   // head-group id
    const size_t idx = g * 32 + d;
    float* bufs[3] = { q, k, ku };
    #pragma unroll
    for (int a = 0; a < 3; a++) {
        float x = bufs[a][idx];
        float v = x * (1.0f / (1.0f + expf(-x)));
        float ss = v * v;
        ss += __shfl_xor(ss, 1);  ss += __shfl_xor(ss, 2);  ss += __shfl_xor(ss, 4);
        ss += __shfl_xor(ss, 8);  ss += __shfl_xor(ss, 16);
        bufs[a][idx] = v * rsqrtf(ss + 1e-6f);
    }
}

// ---- K3a: per-chunk (cumA, cumB) via rank-1 recurrences ----------------
// 256 threads per chunk: row i = t>>3 (0..31), col group jg = t&7 (4 cols).
// 4 waves/chunk -> 4096 waves total = 4 waves/SIMD (vs 1 before).
__global__ __launch_bounds__(256) void scan_pass1(
    const float* __restrict__ kbuf, const float* __restrict__ vbuf,
    const float* __restrict__ kubuf, const float* __restrict__ vubuf,
    const float* __restrict__ betab, const float* __restrict__ alphab,
    const float* __restrict__ gammab, const float* __restrict__ mask,
    float* __restrict__ cumA, float* __restrict__ cumB)
{
    const int bh = blockIdx.x;     // 0..31
    const int c  = blockIdx.y;     // 0..NC_-1
    const int b  = bh >> 3, h = bh & 7;
    const int t  = threadIdx.x;
    const int i  = t >> 3;         // state row
    const int j0 = (t & 7) * 4;    // 4 state cols
    __shared__ float lk [T_][32];
    __shared__ float lv [T_][32];
    __shared__ float lku[T_][32];
    __shared__ float lvu[T_][32];
    __shared__ float lsc[T_][4];   // 0:beta 1:alpha*(1-mask) 2:gamma

    float M[4], Cc[4];
    #pragma unroll
    for (int jj = 0; jj < 4; jj++) { M[jj] = (i == j0 + jj) ? 1.0f : 0.0f; Cc[jj] = 0.0f; }

    // staging: t<128 -> k then ku; t>=128 -> v then vu. 16 rows x 8 quads.
    const float* g0 = (t < 128) ? kbuf  : vbuf;
    const float* g1 = (t < 128) ? kubuf : vubuf;
    const int sr = (t >> 3) & 15, sq = t & 7;

    auto stage = [&](int tile, float4& n0, float4& n1, float& sc) {
        const int row_base = b * S_ + c * CHUNK_ + tile * T_;
        const size_t gb = (size_t)(row_base + sr) * HID_ + h * D_ + sq * 4;
        n0 = *(const float4*)(g0 + gb);
        n1 = *(const float4*)(g1 + gb);
        const int r = t & 15;
        const int rowi = row_base + r;
        if (t < 16)                     sc = betab [(size_t)rowi * H_ + h];
        else if (t >= 64 && t < 80)     sc = alphab[(size_t)rowi * H_ + h] * (1.0f - mask[rowi]);
        else if (t >= 128 && t < 144)   sc = gammab[(size_t)rowi * H_ + h];
    };
    auto commit = [&](float4 n0, float4 n1, float sc) {
        if (t < 128) {
            *(float4*)&lk [sr][sq*4] = n0;
            *(float4*)&lku[sr][sq*4] = n1;
        } else {
            *(float4*)&lv [sr][sq*4] = n0;
            *(float4*)&lvu[sr][sq*4] = n1;
        }
        const int r = t & 15;
        if (t < 16)                     lsc[r][0] = sc;
        else if (t >= 64 && t < 80)     lsc[r][1] = sc;
        else if (t >= 128 && t < 144)   lsc[r][2] = sc;
    };

    float4 p0, p1; float psc = 0.0f;
    stage(0, p0, p1, psc);

    for (int tile = 0; tile < NT_; ++tile) {
        commit(p0, p1, psc);
        __syncthreads();
        float4 n0, n1; float nsc = 0.0f;
        if (tile + 1 < NT_) stage(tile + 1, n0, n1, nsc);

        #pragma unroll
        for (int sl = 0; sl < T_; sl++) {
            const float vi  = lv [sl][i];
            const float vui = lvu[sl][i];
            const float bet = lsc[sl][0];
            const float a   = lsc[sl][1];
            const float bgm = lsc[sl][2];
            float kj[4], kuj[4];
            *(float4*)kj  = *(const float4*)&lk [sl][j0];
            *(float4*)kuj = *(const float4*)&lku[sl][j0];
            float pd = 0.0f, mk = 0.0f, ck = 0.0f;
            #pragma unroll
            for (int jj = 0; jj < 4; jj++) {
                pd += kuj[jj] * kj[jj];
                mk += M[jj]   * kj[jj];
                ck += Cc[jj]  * kj[jj];
            }
            pd += __shfl_xor(pd, 1); pd += __shfl_xor(pd, 2); pd += __shfl_xor(pd, 4);
            mk += __shfl_xor(mk, 1); mk += __shfl_xor(mk, 2); mk += __shfl_xor(mk, 4);
            ck += __shfl_xor(ck, 1); ck += __shfl_xor(ck, 2); ck += __shfl_xor(ck, 4);
            const float abk_m   = a * bet * mk;
            const float ck_coef = bet * vi - a * bet * ck;
            const float wu      = bgm * vui;
            const float bduk    = bet * pd;
            #pragma unroll
            for (int jj = 0; jj < 4; jj++) {
                const float kv = kj[jj];
                const float w  = kuj[jj] - bduk * kv;         // (ku^T @ delta)[j]
                M[jj]  = a * M[jj]  - abk_m   * kv;           // M @ decay
                Cc[jj] = a * Cc[jj] + ck_coef * kv + wu * w;  // C @ decay + update
            }
        }
        __syncthreads();
        p0 = n0; p1 = n1; psc = nsc;
    }
    const size_t ofs = ((size_t)(bh * NC_ + c)) * 1024 + (size_t)i * 32 + j0;
    *(float4*)(cumA + ofs) = make_float4(M[0],  M[1],  M[2],  M[3]);
    *(float4*)(cumB + ofs) = make_float4(Cc[0], Cc[1], Cc[2], Cc[3]);
}

// ---- K3b: sequential chunk composition; emits Sstart per chunk + carry --
__global__ __launch_bounds__(1024) void scan_pass2(
    const float* __restrict__ carry, const float* __restrict__ cumA,
    const float* __restrict__ cumB, float* __restrict__ Sstart,
    float* __restrict__ carry_out)
{
    const int bh = blockIdx.x;
    const int t  = threadIdx.x;
    const int i  = t >> 5;
    const int j  = t & 31;
    __shared__ float Ssh[32][33];
    __shared__ float Ash[32][33];
    const size_t idx = (size_t)i * 32 + j;
    float Sv = carry[(size_t)bh * 1024 + idx];

    float Anext = cumA[((size_t)(bh * NC_)) * 1024 + idx];
    float Bnext = cumB[((size_t)(bh * NC_)) * 1024 + idx];
    for (int c = 0; c < NC_; c++) {
        const size_t ofs = ((size_t)(bh * NC_ + c)) * 1024;
        Sstart[ofs + idx] = Sv;
        Ssh[i][j] = Sv;
        Ash[i][j] = Anext;
        const float Bcur = Bnext;
        __syncthreads();
        if (c + 1 < NC_) {                 // issue next chunk's loads early
            const size_t ofs2 = ofs + 1024;
            Anext = cumA[ofs2 + idx];
            Bnext = cumB[ofs2 + idx];
        }
        float acc = Bcur;
        #pragma unroll 8
        for (int m = 0; m < 32; m++) acc += Ssh[i][m] * Ash[m][j];
        __syncthreads();
        Sv = acc;
    }
    carry_out[(size_t)bh * 1024 + idx] = Sv;
}

// ---- K3c: replay each chunk from Sstart, emit out = S_new . q ----------
// Same 256-thread/chunk mapping as pass1.
__global__ __launch_bounds__(256) void scan_pass3(
    const float* __restrict__ qbuf, const float* __restrict__ kbuf,
    const float* __restrict__ vbuf, const float* __restrict__ kubuf,
    const float* __restrict__ vubuf, const float* __restrict__ betab,
    const float* __restrict__ alphab, const float* __restrict__ gammab,
    const float* __restrict__ mask, const float* __restrict__ Sstart,
    float* __restrict__ outpre)
{
    const int bh = blockIdx.x, c = blockIdx.y;
    const int b  = bh >> 3, h = bh & 7;
    const int t  = threadIdx.x;
    const int i  = t >> 3;
    const int j0 = (t & 7) * 4;
    __shared__ float lk [T_][32];
    __shared__ float lq [T_][32];
    __shared__ float lv [T_][32];
    __shared__ float lku[T_][32];
    __shared__ float lvu[T_][32];
    __shared__ float lsc[T_][4];

    float Sv[4];
    const size_t sofs = ((size_t)(bh * NC_ + c)) * 1024 + (size_t)i * 32 + j0;
    {
        float4 s4 = *(const float4*)(Sstart + sofs);
        Sv[0] = s4.x; Sv[1] = s4.y; Sv[2] = s4.z; Sv[3] = s4.w;
    }

    const float* g0 = (t < 128) ? kbuf  : vbuf;
    const float* g1 = (t < 128) ? kubuf : vubuf;
    const int sr = (t >> 3) & 15, sq = t & 7;

    auto stage = [&](int tile, float4& n0, float4& n1, float4& n2, float& sc) {
        const int row_base = b * S_ + c * CHUNK_ + tile * T_;
        const size_t gb = (size_t)(row_base + sr) * HID_ + h * D_ + sq * 4;
        n0 = *(const float4*)(g0 + gb);
        n1 = *(const float4*)(g1 + gb);
        if (t < 128) n2 = *(const float4*)(qbuf + gb);
        const int r = t & 15;
        const int rowi = row_base + r;
        if (t < 16)                     sc = betab [(size_t)rowi * H_ + h];
        else if (t >= 64 && t < 80)     sc = alphab[(size_t)rowi * H_ + h] * (1.0f - mask[rowi]);
        else if (t >= 128 && t < 144)   sc = gammab[(size_t)rowi * H_ + h];
    };
    auto commit = [&](float4 n0, float4 n1, float4 n2, float sc) {
        if (t < 128) {
            *(float4*)&lk [sr][sq*4] = n0;
            *(float4*)&lku[sr][sq*4] = n1;
            *(float4*)&lq [sr][sq*4] = n2;
        } else {
            *(float4*)&lv [sr][sq*4] = n0;
            *(float4*)&lvu[sr][sq*4] = n1;
        }
        const int r = t & 15;
        if (t < 16)                     lsc[r][0] = sc;
        else if (t >= 64 && t < 80)     lsc[r][1] = sc;
        else if (t >= 128 && t < 144)   lsc[r][2] = sc;
    };

    float4 p0, p1, p2; float psc = 0.0f;
    stage(0, p0, p1, p2, psc);

    for (int tile = 0; tile < NT_; ++tile) {
        commit(p0, p1, p2, psc);
        __syncthreads();
        float4 n0, n1, n2; float nsc = 0.0f;
        if (tile + 1 < NT_) stage(tile + 1, n0, n1, n2, nsc);

        const int row_base = b * S_ + c * CHUNK_ + tile * T_;
        #pragma unroll
        for (int sl = 0; sl < T_; sl++) {
            const float vi  = lv [sl][i];
            const float vui = lvu[sl][i];
            const float bet = lsc[sl][0];
            const float a   = lsc[sl][1];
            const float bgm = lsc[sl][2];
            float kj[4], kuj[4], qj[4];
            *(float4*)kj  = *(const float4*)&lk [sl][j0];
            *(float4*)kuj = *(const float4*)&lku[sl][j0];
            *(float4*)qj  = *(const float4*)&lq [sl][j0];
            float pd = 0.0f, sk = 0.0f;
            #pragma unroll
            for (int jj = 0; jj < 4; jj++) {
                pd += kuj[jj] * kj[jj];
                sk += Sv[jj]  * kj[jj];
            }
            pd += __shfl_xor(pd, 1); pd += __shfl_xor(pd, 2); pd += __shfl_xor(pd, 4);
            sk += __shfl_xor(sk, 1); sk += __shfl_xor(sk, 2); sk += __shfl_xor(sk, 4);
            const float coef_k = bet * vi - a * bet * sk;
            const float wu     = bgm * vui;
            const float bduk   = bet * pd;
            float op = 0.0f;
            #pragma unroll
            for (int jj = 0; jj < 4; jj++) {
                const float kv = kj[jj];
                const float w  = kuj[jj] - bduk * kv;
                Sv[jj] = a * Sv[jj] + coef_k * kv + wu * w;
                op += Sv[jj] * qj[jj];
            }
            op += __shfl_xor(op, 1); op += __shfl_xor(op, 2); op += __shfl_xor(op, 4);
            if ((t & 7) == 0)
                outpre[(size_t)(row_base + sl) * HID_ + h * D_ + i] = op;
        }
        __syncthreads();
        p0 = n0; p1 = n1; p2 = n2; psc = nsc;
    }
}

// ---- K4a: RMS norm + rms_scale -> bf16 hi/lo (one wave per row) --------
__global__ __launch_bounds__(256) void rms_conv_kernel(
    const float* __restrict__ outpre, const float* __restrict__ rms_scale,
    u16* __restrict__ onh, u16* __restrict__ onl)
{
    const int t = threadIdx.x;
    const int lane = t & 63;
    const int row = blockIdx.x * 4 + (t >> 6);
    const float4 v = ((const float4*)(outpre + (size_t)row * HID_))[lane];
    float ss = v.x*v.x + v.y*v.y + v.z*v.z + v.w*v.w;
    ss += __shfl_xor(ss, 1);  ss += __shfl_xor(ss, 2);  ss += __shfl_xor(ss, 4);
    ss += __shfl_xor(ss, 8);  ss += __shfl_xor(ss, 16); ss += __shfl_xor(ss, 32);
    const float rinv = rsqrtf(ss * (1.0f / HID_) + 1e-6f);
    const float4 sc = ((const float4*)rms_scale)[lane];
    ushort4 h, l;
    bfsplit(v.x * rinv * sc.x, h.x, l.x);
    bfsplit(v.y * rinv * sc.y, h.y, l.y);
    bfsplit(v.z * rinv * sc.z, h.z, l.z);
    bfsplit(v.w * rinv * sc.w, h.w, l.w);
    ((ushort4*)(onh + (size_t)row * HID_))[lane] = h;
    ((ushort4*)(onl + (size_t)row * HID_))[lane] = l;
}

// ---- launch ------------------------------------------------------------
extern "C" void kernel_launch(void* const* d_in, const int* in_sizes, int n_in,
                              void* d_out, int out_size, void* d_ws, size_t ws_size,
                              hipStream_t stream)
{
    const float* x      = (const float*)d_in[0];
    const float* action = (const float*)d_in[1];
    const float* mask   = (const float*)d_in[2];
    const float* carry  = (const float*)d_in[3];
    const float* Wq     = (const float*)d_in[4];
    const float* Wk     = (const float*)d_in[5];
    const float* Wv     = (const float*)d_in[6];
    const float* Wbeta  = (const float*)d_in[7];
    const float* Walpha = (const float*)d_in[8];
    const float* Wku    = (const float*)d_in[9];
    const float* Wvu    = (const float*)d_in[10];
    const float* Wgamma = (const float*)d_in[11];
    const float* rms_s  = (const float*)d_in[12];
    const float* Wout   = (const float*)d_in[13];
    const float* bout   = (const float*)d_in[14];

    float* carry_out = (float*)d_out;                       // B*H*D*D = 32768
    float* y         = (float*)d_out + (size_t)BH_ * D_ * D_;

    float* ws = (float*)d_ws;
    float* qb     = ws; ws += (size_t)ROWS_ * HID_;    // qb,kb,vb contiguous
    float* kb     = ws; ws += (size_t)ROWS_ * HID_;
    float* vb     = ws; ws += (size_t)ROWS_ * HID_;
    float* kub    = ws; ws += (size_t)ROWS_ * HID_;
    float* vub    = ws; ws += (size_t)ROWS_ * HID_;
    float* betab  = ws; ws += (size_t)ROWS_ * H_;
    float* alphab = ws; ws += (size_t)ROWS_ * H_;
    float* gammab = ws; ws += (size_t)ROWS_ * H_;
    float* cumA   = ws; ws += (size_t)BH_ * NC_ * D_ * D_;
    float* cumB   = ws; ws += (size_t)BH_ * NC_ * D_ * D_;
    float* Sst    = ws; ws += (size_t)BH_ * NC_ * D_ * D_;
    u16* xh       = (u16*)ws; ws += (size_t)ROWS_ * F_ / 2;   // bf16 halves
    u16* xl       = (u16*)ws; ws += (size_t)ROWS_ * F_ / 2;
    u16* wth      = (u16*)ws; ws += (size_t)3 * HID_ * F_ / 2;
    u16* wtl      = (u16*)ws; ws += (size_t)3 * HID_ * F_ / 2;
    u16* woth     = (u16*)ws; ws += (size_t)F_ * HID_ / 2;
    u16* wotl     = (u16*)ws; ws += (size_t)F_ * HID_ / 2;
    float* outpre = ws; ws += (size_t)ROWS_ * HID_;
    // onh/onl alias qb (free after scan_pass3; each 4 MB, qb is 8 MB)
    u16* onh = (u16*)qb;
    u16* onl = (u16*)qb + (size_t)ROWS_ * HID_;

    conv_x_kernel<<<dim3(ROWS_ * F_ / 4 / 256), 256, 0, stream>>>(x, xh, xl);
    conv_w_kernel<<<dim3(16, 16, 4), 256, 0, stream>>>(
        Wq, Wk, Wv, Wout, wth, wtl, woth, wotl);
    mfma_gemm_kernel<<<dim3(ROWS_/128, HID_/64, 3), 128, 0, stream>>>(
        xh, xl, wth, wtl, qb, F_, HID_, HID_ * F_, ROWS_ * HID_, nullptr);
    gemm_ba_kernel<<<dim3(ROWS_/16), 256, 0, stream>>>(x, Wbeta, Walpha, betab, alphab);
    gemm_act_kernel<<<dim3((ROWS_*520 + 255)/256), 256, 0, stream>>>(
        action, Wku, Wvu, Wgamma, kub, vub, gammab);
    silu_norm_kernel<<<dim3(ROWS_*H_/8), 256, 0, stream>>>(qb, kb, kub);
    scan_pass1<<<dim3(BH_, NC_), 256, 0, stream>>>(
        kb, vb, kub, vub, betab, alphab, gammab, mask, cumA, cumB);
    scan_pass2<<<dim3(BH_), 1024, 0, stream>>>(carry, cumA, cumB, Sst, carry_out);
    scan_pass3<<<dim3(BH_, NC_), 256, 0, stream>>>(
        qb, kb, vb, kub, vub, betab, alphab, gammab, mask, Sst, outpre);
    rms_conv_kernel<<<dim3(ROWS_/4), 256, 0, stream>>>(outpre, rms_s, onh, onl);
    mfma_gemm_kernel<<<dim3(ROWS_/128, F_/64, 1), 128, 0, stream>>>(
        onh, onl, woth, wotl, y, HID_, F_, 0, 0, bout);
}